// Round 6
// baseline (261.844 us; speedup 1.0000x reference)
//
#include <hip/hip_runtime.h>
#include <hip/hip_bf16.h>

#define EMB    512
#define HEAD   64
#define SEQ    4096
#define NB     4
#define NSPLIT 8
#define LDX    72   // padded LDS row stride (144 B, 16B-aligned)

#define SL2E   0.18033688011112042f   // (1/sqrt(64)) * log2(e), folded into Wq

typedef __bf16 bf16x8 __attribute__((ext_vector_type(8)));
typedef float  f32x4  __attribute__((ext_vector_type(4)));

__device__ inline ushort4 cvt4(float4 v) {
    __hip_bfloat16 a = __float2bfloat16(v.x), b = __float2bfloat16(v.y);
    __hip_bfloat16 c = __float2bfloat16(v.z), d = __float2bfloat16(v.w);
    ushort4 r;
    r.x = *(unsigned short*)&a; r.y = *(unsigned short*)&b;
    r.z = *(unsigned short*)&c; r.w = *(unsigned short*)&d;
    return r;
}

// ---------------------------------------------------------------------------
// One-shot W convert: [3][64][512] fp32 -> bf16; Wq pre-scaled by SL2E.
// ---------------------------------------------------------------------------
__global__ __launch_bounds__(256) void cvtw_kernel(
    const float* __restrict__ Wq, const float* __restrict__ Wk,
    const float* __restrict__ Wv, __hip_bfloat16* __restrict__ Wc)
{
    int idx   = blockIdx.x * 256 + threadIdx.x;
    int which = idx >> 13;
    int off   = (idx & 8191) * 4;
    const float* src = (which == 0) ? Wq : (which == 1) ? Wk : Wv;
    float s = (which == 0) ? SL2E : 1.0f;
    float4 v = *(const float4*)(src + off);
    v.x *= s; v.y *= s; v.z *= s; v.w *= s;
    *(ushort4*)(Wc + which * 64 * EMB + off) = cvt4(v);
}

// ---------------------------------------------------------------------------
// Projection (round-3 version, unchanged): X fp32 staged to LDS w/ reg
// double-buffer; W bf16 frags direct from global.
// ---------------------------------------------------------------------------
__global__ __launch_bounds__(256, 3) void proj_kernel(
    const float* __restrict__ q, const float* __restrict__ k, const float* __restrict__ v,
    const __hip_bfloat16* __restrict__ Wc,
    __hip_bfloat16* __restrict__ Qo, __hip_bfloat16* __restrict__ Ko,
    __hip_bfloat16* __restrict__ Vto)
{
    __shared__ __hip_bfloat16 Xs[64][LDX];

    const int which = blockIdx.y;
    const float* __restrict__ x = (which == 0) ? q : (which == 1) ? k : v;
    const __hip_bfloat16* __restrict__ W = Wc + which * 64 * EMB;

    const int tid  = threadIdx.x;
    const int wave = tid >> 6, lane = tid & 63;
    const int l16  = lane & 15, quad = lane >> 4;
    const int r0   = blockIdx.x * 64;
    const float* __restrict__ xb = x + (size_t)r0 * EMB;

    const int sr = tid >> 4;
    const int sc = (tid & 15) << 2;

    const f32x4 z = {0.f, 0.f, 0.f, 0.f};
    f32x4 acc[4] = {z, z, z, z};

    float4 xr[4];
    bf16x8 wf[8];

#define LOADX(dst, e0)                                                        \
    _Pragma("unroll")                                                         \
    for (int it = 0; it < 4; ++it)                                            \
        dst[it] = *(const float4*)(xb + (size_t)(it * 16 + sr) * EMB + (e0) + sc);

#define LOADW(dst, e0)                                                        \
    _Pragma("unroll")                                                         \
    for (int st = 0; st < 2; ++st)                                            \
        _Pragma("unroll")                                                     \
        for (int t = 0; t < 4; ++t)                                           \
            dst[st * 4 + t] = *(const bf16x8*)(W + (size_t)(t * 16 + l16) * EMB \
                                               + (e0) + st * 32 + quad * 8);

    LOADX(xr, 0);
    LOADW(wf, 0);

    #pragma unroll
    for (int c = 0; c < 8; ++c) {
        const int e0 = c * 64;
        if (c) __syncthreads();
        #pragma unroll
        for (int it = 0; it < 4; ++it)
            *(ushort4*)&Xs[it * 16 + sr][sc] = cvt4(xr[it]);
        __syncthreads();

        bf16x8 a0 = *(const bf16x8*)&Xs[wave * 16 + l16][quad * 8];
        bf16x8 a1 = *(const bf16x8*)&Xs[wave * 16 + l16][32 + quad * 8];

        float4 xr2[4];
        bf16x8 wf2[8];
        if (c < 7) { LOADX(xr2, e0 + 64); LOADW(wf2, e0 + 64); }

        #pragma unroll
        for (int t = 0; t < 4; ++t)
            acc[t] = __builtin_amdgcn_mfma_f32_16x16x32_bf16(a0, wf[t], acc[t], 0, 0, 0);
        #pragma unroll
        for (int t = 0; t < 4; ++t)
            acc[t] = __builtin_amdgcn_mfma_f32_16x16x32_bf16(a1, wf[4 + t], acc[t], 0, 0, 0);

        if (c < 7) {
            #pragma unroll
            for (int it = 0; it < 4; ++it) xr[it] = xr2[it];
            #pragma unroll
            for (int j = 0; j < 8; ++j) wf[j] = wf2[j];
        }
    }
#undef LOADX
#undef LOADW

    #pragma unroll
    for (int t = 0; t < 4; ++t) {
        #pragma unroll
        for (int r = 0; r < 4; ++r) {
            int row = r0 + wave * 16 + quad * 4 + r;
            int h   = t * 16 + l16;
            __hip_bfloat16 val = __float2bfloat16(acc[t][r]);
            if (which == 0) {
                Qo[(size_t)row * HEAD + h] = val;   // already scaled via Wc
            } else if (which == 1) {
                Ko[(size_t)row * HEAD + h] = val;
            } else {
                int b = row >> 12, s = row & (SEQ - 1);
                Vto[((size_t)b * HEAD + h) * SEQ + s] = val;
            }
        }
    }
}

// ---------------------------------------------------------------------------
// Flash attention, BARRIER-FREE: all MFMA fragments except P load directly
// global->register (Q/K/V frag layouts are contiguous 16B row-chunks of
// Qb/Kb/Vt; each tile byte touched once per wave, L1/L2-hot). No
// __syncthreads anywhere -> waves pipeline independently across KV iters.
// Only P does a wave-private LDS round-trip (C-layout -> A-layout).
// l accumulated via MFMA against a ones-vector (C-layout rows align with O;
// no shuffles). Fixed-m softmax (Q pre-scaled by SL2E via Wc).
// Disjoint fp32 partials per split (R3/R4 lesson: no atomics, no reg-prefetch
// + launch_bounds(,N) combos — phantom-write codegen).
// ---------------------------------------------------------------------------
__global__ __launch_bounds__(256) void attn_kernel(
    const __hip_bfloat16* __restrict__ Qb, const __hip_bfloat16* __restrict__ Kb,
    const __hip_bfloat16* __restrict__ Vt, float* __restrict__ Op,
    float* __restrict__ lp)
{
    __shared__ __hip_bfloat16 Ps[64][LDX];   // P staging only (wave-private strips)

    const int tid  = threadIdx.x;
    const int wave = tid >> 6, lane = tid & 63;
    const int l16  = lane & 15, quad = lane >> 4;
    const int b    = blockIdx.y;
    const int q0   = blockIdx.x * 64;
    const int j0b  = blockIdx.z * (SEQ / NSPLIT);

    // Q A-frags: A[m=l16][k=st*32+quad*8+j] = Q[q0+wave*16+l16][d]
    const __hip_bfloat16* qrow = Qb + ((size_t)b * SEQ + q0 + wave * 16 + l16) * HEAD + quad * 8;
    bf16x8 qf0 = *(const bf16x8*)(qrow);
    bf16x8 qf1 = *(const bf16x8*)(qrow + 32);

    // K B-frag base: K[kv=j0+t*16+l16][d=st*32+quad*8+j]
    const __hip_bfloat16* kbase = Kb + (size_t)b * SEQ * HEAD + quad * 8;
    // V B-frag base: V^T[d=t*16+l16][kv=j0+st*32+quad*8+j]
    const __hip_bfloat16* vbase = Vt + ((size_t)b * HEAD + l16) * SEQ + quad * 8;

    const f32x4 z = {0.f, 0.f, 0.f, 0.f};
    f32x4 oacc[4] = {z, z, z, z};
    f32x4 lacc = z;

    const __hip_bfloat16 one_bf = __float2bfloat16(1.0f);
    bf16x8 ones;
    #pragma unroll
    for (int j = 0; j < 8; ++j) ones[j] = *(const __bf16*)&one_bf;

    for (int jt = 0; jt < SEQ / NSPLIT; jt += 64) {
        const int j0 = j0b + jt;

        // S = Q K^T  (wave: 16 q-rows x 64 kv), K frags direct from global
        f32x4 sacc[4] = {z, z, z, z};
        #pragma unroll
        for (int st = 0; st < 2; ++st) {
            bf16x8 a = (st == 0) ? qf0 : qf1;
            #pragma unroll
            for (int t = 0; t < 4; ++t) {
                bf16x8 kf = *(const bf16x8*)(kbase + (size_t)(j0 + t * 16 + l16) * HEAD + st * 32);
                sacc[t] = __builtin_amdgcn_mfma_f32_16x16x32_bf16(a, kf, sacc[t], 0, 0, 0);
            }
        }

        // p = exp2(s); Q pre-scaled -> no mul, no max, no shuffles
        #pragma unroll
        for (int r = 0; r < 4; ++r) {
            #pragma unroll
            for (int t = 0; t < 4; ++t) {
                float p = __builtin_amdgcn_exp2f(sacc[t][r]);
                Ps[wave * 16 + quad * 4 + r][t * 16 + l16] = __float2bfloat16(p);
            }
        }

        // O += P V ; l += P * ones  (V frags direct from global)
        #pragma unroll
        for (int st = 0; st < 2; ++st) {
            bf16x8 pf = *(const bf16x8*)&Ps[wave * 16 + l16][st * 32 + quad * 8];
            lacc = __builtin_amdgcn_mfma_f32_16x16x32_bf16(pf, ones, lacc, 0, 0, 0);
            #pragma unroll
            for (int t = 0; t < 4; ++t) {
                bf16x8 vf = *(const bf16x8*)(vbase + (size_t)(t * 16) * SEQ + j0 + st * 32);
                oacc[t] = __builtin_amdgcn_mfma_f32_16x16x32_bf16(pf, vf, oacc[t], 0, 0, 0);
            }
        }
    }

    // epilogue: lacc[r] = l for q-row quad*4+r (identical across cols)
    const size_t pb = (size_t)(blockIdx.z * NB + b) * SEQ;
    if (l16 == 0) {
        #pragma unroll
        for (int r = 0; r < 4; ++r)
            lp[pb + q0 + wave * 16 + quad * 4 + r] = lacc[r];
    }
    #pragma unroll
    for (int t = 0; t < 4; ++t)
        #pragma unroll
        for (int r = 0; r < 4; ++r)
            Op[(pb + q0 + wave * 16 + quad * 4 + r) * HEAD + t * 16 + l16] = oacc[t][r];
}

// ---------------------------------------------------------------------------
// Merge: out = (sum_s O_s) / (sum_s l_s)
// ---------------------------------------------------------------------------
__global__ __launch_bounds__(256) void merge_kernel(
    const float* __restrict__ Op, const float* __restrict__ lp,
    float* __restrict__ out)
{
    int idx = blockIdx.x * 256 + threadIdx.x;   // [0, B*S*16)
    int bq  = idx >> 4;
    int c4  = (idx & 15) * 4;
    float4 acc = {0.f, 0.f, 0.f, 0.f};
    float  l   = 0.f;
    #pragma unroll
    for (int s = 0; s < NSPLIT; ++s) {
        float4 o = *(const float4*)(Op + ((size_t)s * NB * SEQ + bq) * HEAD + c4);
        acc.x += o.x; acc.y += o.y; acc.z += o.z; acc.w += o.w;
        l += lp[(size_t)s * NB * SEQ + bq];
    }
    float inv = 1.f / l;
    float4 r = {acc.x * inv, acc.y * inv, acc.z * inv, acc.w * inv};
    *(float4*)(out + (size_t)bq * HEAD + c4) = r;
}

extern "C" void kernel_launch(void* const* d_in, const int* in_sizes, int n_in,
                              void* d_out, int out_size, void* d_ws, size_t ws_size,
                              hipStream_t stream) {
    const float* q  = (const float*)d_in[0];
    const float* k  = (const float*)d_in[1];
    const float* v  = (const float*)d_in[2];
    const float* Wq = (const float*)d_in[3];
    const float* Wk = (const float*)d_in[4];
    const float* Wv = (const float*)d_in[5];
    float* out = (float*)d_out;

    // ws: Qb 2MB | Kb 2MB | Vt 2MB | Wc 192KB | Op 32MB | lp 512KB (~38.7MB)
    __hip_bfloat16* Qb = (__hip_bfloat16*)d_ws;
    __hip_bfloat16* Kb = Qb + (size_t)NB * SEQ * HEAD;
    __hip_bfloat16* Vt = Kb + (size_t)NB * SEQ * HEAD;
    __hip_bfloat16* Wc = Vt + (size_t)NB * SEQ * HEAD;
    float* Op = (float*)(Wc + 3 * 64 * EMB);
    float* lp = Op + (size_t)NSPLIT * NB * SEQ * HEAD;

    cvtw_kernel<<<96, 256, 0, stream>>>(Wq, Wk, Wv, Wc);

    dim3 pgrid(NB * SEQ / 64, 3);
    proj_kernel<<<pgrid, dim3(256), 0, stream>>>(q, k, v, Wc, Qb, Kb, Vt);

    dim3 agrid(SEQ / 64, NB, NSPLIT);
    attn_kernel<<<agrid, dim3(256), 0, stream>>>(Qb, Kb, Vt, Op, lp);

    merge_kernel<<<(NB * SEQ * 16) / 256, dim3(256), 0, stream>>>(Op, lp, out);
}

// Round 7
// 180.103 us; speedup vs baseline: 1.4539x; 1.4539x over previous
//
#include <hip/hip_runtime.h>
#include <hip/hip_bf16.h>

#define EMB    512
#define HEAD   64
#define SEQ    4096
#define NB     4
#define NSPLIT 8
#define LDX    72   // padded LDS row stride (144 B, 16B-aligned)

#define SL2E   0.18033688011112042f   // (1/sqrt(64)) * log2(e), folded into Wq

typedef __bf16 bf16x8 __attribute__((ext_vector_type(8)));
typedef float  f32x4  __attribute__((ext_vector_type(4)));

__device__ inline ushort4 cvt4(float4 v) {
    __hip_bfloat16 a = __float2bfloat16(v.x), b = __float2bfloat16(v.y);
    __hip_bfloat16 c = __float2bfloat16(v.z), d = __float2bfloat16(v.w);
    ushort4 r;
    r.x = *(unsigned short*)&a; r.y = *(unsigned short*)&b;
    r.z = *(unsigned short*)&c; r.w = *(unsigned short*)&d;
    return r;
}

// ---------------------------------------------------------------------------
// One-shot W convert: [3][64][512] fp32 -> bf16; Wq pre-scaled by SL2E.
// ---------------------------------------------------------------------------
__global__ __launch_bounds__(256) void cvtw_kernel(
    const float* __restrict__ Wq, const float* __restrict__ Wk,
    const float* __restrict__ Wv, __hip_bfloat16* __restrict__ Wc)
{
    int idx   = blockIdx.x * 256 + threadIdx.x;
    int which = idx >> 13;
    int off   = (idx & 8191) * 4;
    const float* src = (which == 0) ? Wq : (which == 1) ? Wk : Wv;
    float s = (which == 0) ? SL2E : 1.0f;
    float4 v = *(const float4*)(src + off);
    v.x *= s; v.y *= s; v.z *= s; v.w *= s;
    *(ushort4*)(Wc + which * 64 * EMB + off) = cvt4(v);
}

// ---------------------------------------------------------------------------
// Projection: X[16384,512] fp32 @ Wc[64,512]^T(bf16) -> bf16.
// 32 rows/block (grid 1536 = 6 blocks/CU; the old 64-row grid of 768 capped
// residency at 3/CU, which was proj's binding constraint). 4 waves: wave w
// does row-strip (w&1), col-half (w>>1). X staged to LDS w/ reg double-
// buffer; W bf16 frags direct from global (L1-hot).
// ---------------------------------------------------------------------------
__global__ __launch_bounds__(256) void proj_kernel(
    const float* __restrict__ q, const float* __restrict__ k, const float* __restrict__ v,
    const __hip_bfloat16* __restrict__ Wc,
    __hip_bfloat16* __restrict__ Qo, __hip_bfloat16* __restrict__ Ko,
    __hip_bfloat16* __restrict__ Vto)
{
    __shared__ __hip_bfloat16 Xs[32][LDX];

    const int which = blockIdx.y;
    const float* __restrict__ x = (which == 0) ? q : (which == 1) ? k : v;
    const __hip_bfloat16* __restrict__ W = Wc + which * 64 * EMB;

    const int tid  = threadIdx.x;
    const int wave = tid >> 6, lane = tid & 63;
    const int l16  = lane & 15, quad = lane >> 4;
    const int rs   = (wave & 1) * 16;        // row strip within block
    const int ch   = wave >> 1;              // col half: t in {2ch, 2ch+1}
    const int r0   = blockIdx.x * 32;
    const float* __restrict__ xb = x + (size_t)r0 * EMB;

    const int sr = tid >> 4;                 // 0..15 staging row base
    const int sc = (tid & 15) << 2;

    const f32x4 z = {0.f, 0.f, 0.f, 0.f};
    f32x4 acc[2] = {z, z};

    float4 xr[2];
    bf16x8 wf[4];

#define LOADX(dst, e0)                                                        \
    _Pragma("unroll")                                                         \
    for (int it = 0; it < 2; ++it)                                            \
        dst[it] = *(const float4*)(xb + (size_t)(it * 16 + sr) * EMB + (e0) + sc);

#define LOADW(dst, e0)                                                        \
    _Pragma("unroll")                                                         \
    for (int st = 0; st < 2; ++st)                                            \
        _Pragma("unroll")                                                     \
        for (int tt = 0; tt < 2; ++tt)                                        \
            dst[st * 2 + tt] = *(const bf16x8*)(W + (size_t)((ch * 2 + tt) * 16 + l16) * EMB \
                                                + (e0) + st * 32 + quad * 8);

    LOADX(xr, 0);
    LOADW(wf, 0);

    #pragma unroll
    for (int c = 0; c < 8; ++c) {
        const int e0 = c * 64;
        if (c) __syncthreads();
        #pragma unroll
        for (int it = 0; it < 2; ++it)
            *(ushort4*)&Xs[it * 16 + sr][sc] = cvt4(xr[it]);
        __syncthreads();

        bf16x8 a0 = *(const bf16x8*)&Xs[rs + l16][quad * 8];
        bf16x8 a1 = *(const bf16x8*)&Xs[rs + l16][32 + quad * 8];

        float4 xr2[2];
        bf16x8 wf2[4];
        if (c < 7) { LOADX(xr2, e0 + 64); LOADW(wf2, e0 + 64); }

        #pragma unroll
        for (int tt = 0; tt < 2; ++tt)
            acc[tt] = __builtin_amdgcn_mfma_f32_16x16x32_bf16(a0, wf[tt], acc[tt], 0, 0, 0);
        #pragma unroll
        for (int tt = 0; tt < 2; ++tt)
            acc[tt] = __builtin_amdgcn_mfma_f32_16x16x32_bf16(a1, wf[2 + tt], acc[tt], 0, 0, 0);

        if (c < 7) {
            #pragma unroll
            for (int it = 0; it < 2; ++it) xr[it] = xr2[it];
            #pragma unroll
            for (int j = 0; j < 4; ++j) wf[j] = wf2[j];
        }
    }
#undef LOADX
#undef LOADW

    #pragma unroll
    for (int tt = 0; tt < 2; ++tt) {
        #pragma unroll
        for (int r = 0; r < 4; ++r) {
            int row = r0 + rs + quad * 4 + r;
            int h   = (ch * 2 + tt) * 16 + l16;
            __hip_bfloat16 val = __float2bfloat16(acc[tt][r]);
            if (which == 0) {
                Qo[(size_t)row * HEAD + h] = val;   // already scaled via Wc
            } else if (which == 1) {
                Ko[(size_t)row * HEAD + h] = val;
            } else {
                int b = row >> 12, s = row & (SEQ - 1);
                Vto[((size_t)b * HEAD + h) * SEQ + s] = val;
            }
        }
    }
}

// ---------------------------------------------------------------------------
// Flash attention, 128 q-rows/block (4 waves x 2 strips of 16): K/V staged in
// LDS (R5 proven structure — R6 lesson: direct V frag loads are 16-way
// scattered, never again), Q frags direct from global (dense 16B loads).
// LDS bytes per q-row 1.7x lower than the 64-row version; KV FETCH halves.
// Fixed-m softmax (Q pre-scaled by SL2E); l via MFMA against ones.
// Disjoint fp32 partials per split; merge_kernel combines.
// ---------------------------------------------------------------------------
__global__ __launch_bounds__(256) void attn_kernel(
    const __hip_bfloat16* __restrict__ Qb, const __hip_bfloat16* __restrict__ Kb,
    const __hip_bfloat16* __restrict__ Vt, float* __restrict__ Op,
    float* __restrict__ lp)
{
    __shared__ __hip_bfloat16 Ks[64][LDX];
    __shared__ __hip_bfloat16 Vs[64][LDX];    // V^T tile [d][kv]
    __shared__ __hip_bfloat16 Ps[128][LDX];   // P staging (wave-private strips)

    const int tid  = threadIdx.x;
    const int wave = tid >> 6, lane = tid & 63;
    const int l16  = lane & 15, quad = lane >> 4;
    const int b    = blockIdx.y;
    const int q0   = blockIdx.x * 128;
    const int j0b  = blockIdx.z * (SEQ / NSPLIT);

    // Q A-frags direct from global: rows q0 + wave*32 + s*16 + l16
    bf16x8 qf[2][2];
    #pragma unroll
    for (int s = 0; s < 2; ++s) {
        const __hip_bfloat16* qrow =
            Qb + ((size_t)b * SEQ + q0 + wave * 32 + s * 16 + l16) * HEAD + quad * 8;
        qf[s][0] = *(const bf16x8*)(qrow);
        qf[s][1] = *(const bf16x8*)(qrow + 32);
    }

    const f32x4 z = {0.f, 0.f, 0.f, 0.f};
    f32x4 oacc[2][4] = {{z, z, z, z}, {z, z, z, z}};
    f32x4 lacc[2] = {z, z};

    const __hip_bfloat16 one_bf = __float2bfloat16(1.0f);
    bf16x8 ones;
    #pragma unroll
    for (int j = 0; j < 8; ++j) ones[j] = *(const __bf16*)&one_bf;

    for (int jt = 0; jt < SEQ / NSPLIT; jt += 64) {
        const int j0 = j0b + jt;
        __syncthreads();
        for (int i = tid; i < 512; i += 256) {
            int r = i >> 3, c8 = (i & 7) * 8;
            *(uint4*)&Ks[r][c8] =
                *(const uint4*)(Kb + ((size_t)b * SEQ + j0 + r) * HEAD + c8);
            *(uint4*)&Vs[r][c8] =
                *(const uint4*)(Vt + ((size_t)b * HEAD + r) * SEQ + j0 + c8);
        }
        __syncthreads();

        // S = Q K^T  (wave: 2 strips x 16 q-rows x 64 kv)
        f32x4 sacc[2][4] = {{z, z, z, z}, {z, z, z, z}};
        #pragma unroll
        for (int st = 0; st < 2; ++st) {
            #pragma unroll
            for (int t = 0; t < 4; ++t) {
                bf16x8 kf = *(const bf16x8*)&Ks[t * 16 + l16][st * 32 + quad * 8];
                #pragma unroll
                for (int s = 0; s < 2; ++s)
                    sacc[s][t] = __builtin_amdgcn_mfma_f32_16x16x32_bf16(qf[s][st], kf, sacc[s][t], 0, 0, 0);
            }
        }

        // p = exp2(s); Q pre-scaled -> no mul, no max, no shuffles
        #pragma unroll
        for (int s = 0; s < 2; ++s)
            #pragma unroll
            for (int r = 0; r < 4; ++r)
                #pragma unroll
                for (int t = 0; t < 4; ++t) {
                    float p = __builtin_amdgcn_exp2f(sacc[s][t][r]);
                    Ps[wave * 32 + s * 16 + quad * 4 + r][t * 16 + l16] = __float2bfloat16(p);
                }

        // O += P V ; l += P * ones  (P strips wave-private: lgkmcnt-only RAW)
        #pragma unroll
        for (int s = 0; s < 2; ++s) {
            #pragma unroll
            for (int st = 0; st < 2; ++st) {
                bf16x8 pf = *(const bf16x8*)&Ps[wave * 32 + s * 16 + l16][st * 32 + quad * 8];
                lacc[s] = __builtin_amdgcn_mfma_f32_16x16x32_bf16(pf, ones, lacc[s], 0, 0, 0);
                #pragma unroll
                for (int t = 0; t < 4; ++t) {
                    bf16x8 vf = *(const bf16x8*)&Vs[t * 16 + l16][st * 32 + quad * 8];
                    oacc[s][t] = __builtin_amdgcn_mfma_f32_16x16x32_bf16(pf, vf, oacc[s][t], 0, 0, 0);
                }
            }
        }
    }

    // epilogue: disjoint fp32 partials
    const size_t pb = (size_t)(blockIdx.z * NB + b) * SEQ;
    #pragma unroll
    for (int s = 0; s < 2; ++s) {
        const size_t row0 = pb + q0 + wave * 32 + s * 16 + quad * 4;
        if (l16 == 0) {
            #pragma unroll
            for (int r = 0; r < 4; ++r)
                lp[row0 + r] = lacc[s][r];
        }
        #pragma unroll
        for (int t = 0; t < 4; ++t)
            #pragma unroll
            for (int r = 0; r < 4; ++r)
                Op[(row0 + r) * HEAD + t * 16 + l16] = oacc[s][t][r];
    }
}

// ---------------------------------------------------------------------------
// Merge: out = (sum_s O_s) / (sum_s l_s)
// ---------------------------------------------------------------------------
__global__ __launch_bounds__(256) void merge_kernel(
    const float* __restrict__ Op, const float* __restrict__ lp,
    float* __restrict__ out)
{
    int idx = blockIdx.x * 256 + threadIdx.x;   // [0, B*S*16)
    int bq  = idx >> 4;
    int c4  = (idx & 15) * 4;
    float4 acc = {0.f, 0.f, 0.f, 0.f};
    float  l   = 0.f;
    #pragma unroll
    for (int s = 0; s < NSPLIT; ++s) {
        float4 o = *(const float4*)(Op + ((size_t)s * NB * SEQ + bq) * HEAD + c4);
        acc.x += o.x; acc.y += o.y; acc.z += o.z; acc.w += o.w;
        l += lp[(size_t)s * NB * SEQ + bq];
    }
    float inv = 1.f / l;
    float4 r = {acc.x * inv, acc.y * inv, acc.z * inv, acc.w * inv};
    *(float4*)(out + (size_t)bq * HEAD + c4) = r;
}

extern "C" void kernel_launch(void* const* d_in, const int* in_sizes, int n_in,
                              void* d_out, int out_size, void* d_ws, size_t ws_size,
                              hipStream_t stream) {
    const float* q  = (const float*)d_in[0];
    const float* k  = (const float*)d_in[1];
    const float* v  = (const float*)d_in[2];
    const float* Wq = (const float*)d_in[3];
    const float* Wk = (const float*)d_in[4];
    const float* Wv = (const float*)d_in[5];
    float* out = (float*)d_out;

    // ws: Qb 2MB | Kb 2MB | Vt 2MB | Wc 192KB | Op 32MB | lp 512KB (~38.7MB)
    __hip_bfloat16* Qb = (__hip_bfloat16*)d_ws;
    __hip_bfloat16* Kb = Qb + (size_t)NB * SEQ * HEAD;
    __hip_bfloat16* Vt = Kb + (size_t)NB * SEQ * HEAD;
    __hip_bfloat16* Wc = Vt + (size_t)NB * SEQ * HEAD;
    float* Op = (float*)(Wc + 3 * 64 * EMB);
    float* lp = Op + (size_t)NSPLIT * NB * SEQ * HEAD;

    cvtw_kernel<<<96, 256, 0, stream>>>(Wq, Wk, Wv, Wc);

    dim3 pgrid(NB * SEQ / 32, 3);
    proj_kernel<<<pgrid, dim3(256), 0, stream>>>(q, k, v, Wc, Qb, Kb, Vt);

    dim3 agrid(SEQ / 128, NB, NSPLIT);
    attn_kernel<<<agrid, dim3(256), 0, stream>>>(Qb, Kb, Vt, Op, lp);

    merge_kernel<<<(NB * SEQ * 16) / 256, dim3(256), 0, stream>>>(Op, lp, out);
}